// Round 4
// baseline (481.345 us; speedup 1.0000x reference)
//
#include <hip/hip_runtime.h>

#define CC 33
#define WAVE 64
#define PF 8  // prefetch depth == unroll factor

__device__ __forceinline__ float wave_sum64(float v) {
#pragma unroll
  for (int k = 32; k >= 1; k >>= 1) v += __shfl_xor(v, k, 64);
  return v;
}

__device__ __forceinline__ int wave_isum64(int v) {
#pragma unroll
  for (int k = 32; k >= 1; k >>= 1) v += __shfl_xor(v, k, 64);
  return v;
}

// broadcast lane `lane` (compile-time) of p to all lanes via v_readlane
__device__ __forceinline__ float rl(float v, int lane) {
  return __uint_as_float(__builtin_amdgcn_readlane(__float_as_uint(v), lane));
}

// ---------------------------------------------------------------------------
// Forward-algorithm scan, one wave per sequence, lane j owns state j.
// LINEAR-space recurrence: p_j <- (sum_i p_i * exp(trans[i][j])) * exp(em_j),
// renormalized by p[0] every 4 steps with log accumulated into `logoff`.
// alpha_j == log(p_j) + logoff at all times (shift-invariant, exact math).
// Emissions/mask prefetched PF=8 steps ahead into registers.
// __launch_bounds__(64, 1): grid is only 512 waves (2/CU) -- occupancy is
// grid-limited, so give the wave the full VGPR budget; without this the
// compiler allocates 32 VGPRs and spills etcol[] to AGPRs, adding a
// v_accvgpr_read to every FMA of the inner dot (measured: 611 cyc/step).
// ---------------------------------------------------------------------------
__global__ __launch_bounds__(WAVE, 1) void crf_scan_kernel(
    const float* __restrict__ emissions, const int* __restrict__ mask,
    const float* __restrict__ transitions, const float* __restrict__ start_t,
    const float* __restrict__ end_t, const float* __restrict__ tmask,
    const float* __restrict__ smask, const float* __restrict__ emask,
    float* __restrict__ logz_out, int T) {
  const int b = blockIdx.x;
  const int j = threadIdx.x;

  __shared__ float s_trans[CC * CC];
  for (int k = j; k < CC * CC; k += WAVE) s_trans[k] = transitions[k] + tmask[k];
  __syncthreads();

  // lane j holds exp(trans[i][j]) for all i (column j); lanes >= CC hold 0.
  float etcol[CC];
#pragma unroll
  for (int i = 0; i < CC; ++i)
    etcol[i] = (j < CC) ? __expf(s_trans[i * CC + j]) : 0.0f;

  const float* __restrict__ emb = emissions + (size_t)b * T * CC;
  const int* __restrict__ maskb = mask + (size_t)b * T;

  const float NEG = -INFINITY;
  // p = exp(alpha0); lanes >= CC stay exactly 0 forever.
  float p = (j < CC) ? __expf(start_t[j] + smask[j] + emb[j]) : 0.0f;
  float logoff = 0.0f;

  // prefetch ring: raw emission + mask for steps t0..t0+PF-1
  float em_pre[PF];
  int mc[PF];
#pragma unroll
  for (int k = 0; k < PF; ++k) {
    int t = 1 + k;
    int tc = t < T ? t : T - 1;
    em_pre[k] = (j < CC) ? emb[(size_t)tc * CC + j] : NEG;
    mc[k] = maskb[tc];
  }

  int t0 = 1;
  for (; t0 + PF <= T; t0 += PF) {
#pragma unroll
    for (int k = 0; k < PF; ++k) {
      float emk = em_pre[k];
      int mt = mc[k];
      // issue prefetch for t0+PF+k (consumed 8 steps later)
      {
        int tn = t0 + PF + k;
        int tc = tn < T ? tn : T - 1;
        em_pre[k] = (j < CC) ? emb[(size_t)tc * CC + j] : NEG;
        mc[k] = maskb[tc];
      }
      float eemk = __expf(emk);  // off the p-chain (dep: 8-steps-old load)

      // dot: s_j = sum_i p_i * etcol[i], broadcast via readlane
      float a0 = 0.f, a1 = 0.f, a2 = 0.f, a3 = 0.f;
#pragma unroll
      for (int i = 0; i < 32; i += 4) {
        a0 = fmaf(rl(p, i + 0), etcol[i + 0], a0);
        a1 = fmaf(rl(p, i + 1), etcol[i + 1], a1);
        a2 = fmaf(rl(p, i + 2), etcol[i + 2], a2);
        a3 = fmaf(rl(p, i + 3), etcol[i + 3], a3);
      }
      float s = ((a0 + a1) + (a2 + a3)) + rl(p, 32) * etcol[32];

      if ((k & 3) == 0) {
        // renormalize by previous p[0] (uniform), fold into the emission mul
        float r = rl(p, 0);
        float rs = __builtin_amdgcn_rcpf(r);
        float pn = s * (eemk * rs);
        p = mt ? pn : p;
        logoff += mt ? __logf(r) : 0.0f;
      } else {
        float pn = s * eemk;
        p = mt ? pn : p;
      }
    }
  }
  // tail (< PF steps), fully unrolled so slot indices stay compile-time
#pragma unroll
  for (int k = 0; k < PF; ++k) {
    if (t0 + k < T) {
      float emk = em_pre[k];
      int mt = mc[k];
      float eemk = __expf(emk);
      float a0 = 0.f, a1 = 0.f, a2 = 0.f, a3 = 0.f;
#pragma unroll
      for (int i = 0; i < 32; i += 4) {
        a0 = fmaf(rl(p, i + 0), etcol[i + 0], a0);
        a1 = fmaf(rl(p, i + 1), etcol[i + 1], a1);
        a2 = fmaf(rl(p, i + 2), etcol[i + 2], a2);
        a3 = fmaf(rl(p, i + 3), etcol[i + 3], a3);
      }
      float s = ((a0 + a1) + (a2 + a3)) + rl(p, 32) * etcol[32];
      if ((k & 3) == 0) {
        float r = rl(p, 0);
        float rs = __builtin_amdgcn_rcpf(r);
        float pn = s * (eemk * rs);
        p = mt ? pn : p;
        logoff += mt ? __logf(r) : 0.0f;
      } else {
        float pn = s * eemk;
        p = mt ? pn : p;
      }
    }
  }

  // log_z = logoff + log( sum_j p_j * exp(end_s_j) )
  float eend = (j < CC) ? __expf(end_t[j] + emask[j]) : 0.0f;
  float sum = wave_sum64(p * eend);
  if (j == 0) logz_out[b] = logoff + __logf(sum);
}

// ---------------------------------------------------------------------------
// Gold-path score: embarrassingly parallel over (b, t).
// ---------------------------------------------------------------------------
__global__ __launch_bounds__(256) void crf_score_kernel(
    const float* __restrict__ emissions, const int* __restrict__ tags,
    const int* __restrict__ mask, const float* __restrict__ transitions,
    const float* __restrict__ start_t, const float* __restrict__ end_t,
    const float* __restrict__ tmask, const float* __restrict__ smask,
    const float* __restrict__ emask, float* __restrict__ score_out, int T) {
  const int b = blockIdx.x;
  const int tid = threadIdx.x;

  __shared__ float s_trans[CC * CC];
  for (int k = tid; k < CC * CC; k += 256) s_trans[k] = transitions[k] + tmask[k];
  __syncthreads();

  const float* __restrict__ emb = emissions + (size_t)b * T * CC;
  const int* __restrict__ tagb = tags + (size_t)b * T;
  const int* __restrict__ maskb = mask + (size_t)b * T;

  float local = 0.f;
  int llen = 0;
  for (int t = tid; t < T; t += 256) {
    int mt = maskb[t];
    llen += (mt != 0);
    if (t >= 1) {
      int cur = tagb[t];
      int prev = tagb[t - 1];
      float v = s_trans[prev * CC + cur] + emb[(size_t)t * CC + cur];
      local += (mt != 0) ? v : 0.f;
    }
  }

  local = wave_sum64(local);
  llen = wave_isum64(llen);
  __shared__ float ws[4];
  __shared__ int wl[4];
  if ((tid & 63) == 0) { ws[tid >> 6] = local; wl[tid >> 6] = llen; }
  __syncthreads();
  if (tid == 0) {
    float total = ws[0] + ws[1] + ws[2] + ws[3];
    int len = wl[0] + wl[1] + wl[2] + wl[3];
    int tag0 = tagb[0];
    total += start_t[tag0] + smask[tag0] + emb[tag0];
    if (len < 1) len = 1;
    int last = tagb[len - 1];
    total += end_t[last] + emask[last];
    score_out[b] = total;
  }
}

__global__ __launch_bounds__(256) void reduce_mean_kernel(
    const float* __restrict__ logz, const float* __restrict__ score,
    float* __restrict__ out, int n) {
  int tid = threadIdx.x;
  float s = 0.f;
  for (int i = tid; i < n; i += 256) s += logz[i] - score[i];
  s = wave_sum64(s);
  __shared__ float ws[4];
  if ((tid & 63) == 0) ws[tid >> 6] = s;
  __syncthreads();
  if (tid == 0) out[0] = (ws[0] + ws[1] + ws[2] + ws[3]) / (float)n;
}

extern "C" void kernel_launch(void* const* d_in, const int* in_sizes, int n_in,
                              void* d_out, int out_size, void* d_ws, size_t ws_size,
                              hipStream_t stream) {
  const float* emissions = (const float*)d_in[0];
  const int* tags = (const int*)d_in[1];
  const int* mask = (const int*)d_in[2];
  const float* transitions = (const float*)d_in[3];
  const float* start_t = (const float*)d_in[4];
  const float* end_t = (const float*)d_in[5];
  const float* tmask = (const float*)d_in[6];
  const float* smask = (const float*)d_in[7];
  const float* emask = (const float*)d_in[8];

  const int T = 2048;          // fixed problem shape
  const int BT = in_sizes[1];  // B*T
  const int B = BT / T;

  float* logz = (float*)d_ws;       // B floats
  float* score = logz + B;          // B floats

  crf_scan_kernel<<<B, WAVE, 0, stream>>>(emissions, mask, transitions, start_t,
                                          end_t, tmask, smask, emask, logz, T);
  crf_score_kernel<<<B, 256, 0, stream>>>(emissions, tags, mask, transitions,
                                          start_t, end_t, tmask, smask, emask,
                                          score, T);
  reduce_mean_kernel<<<1, 256, 0, stream>>>(logz, score, (float*)d_out, B);
}

// Round 5
// 480.822 us; speedup vs baseline: 1.0011x; 1.0011x over previous
//
#include <hip/hip_runtime.h>

#define CC 33
#define WAVE 64
#define PF 8  // prefetch depth == unroll factor

__device__ __forceinline__ float wave_sum64(float v) {
#pragma unroll
  for (int k = 32; k >= 1; k >>= 1) v += __shfl_xor(v, k, 64);
  return v;
}

__device__ __forceinline__ int wave_isum64(int v) {
#pragma unroll
  for (int k = 32; k >= 1; k >>= 1) v += __shfl_xor(v, k, 64);
  return v;
}

// broadcast lane `lane` (compile-time) of p to all lanes via v_readlane
__device__ __forceinline__ float rl(float v, int lane) {
  return __uint_as_float(__builtin_amdgcn_readlane(__float_as_uint(v), lane));
}

// ---------------------------------------------------------------------------
// Forward-algorithm scan, one wave per sequence, lane j owns state j.
// LINEAR-space recurrence: p_j <- (sum_i p_i * exp(trans[i][j])) * exp(em_j),
// renormalized by p[0] every 4 steps with log accumulated into `logoff`.
// alpha_j == log(p_j) + logoff at all times (shift-invariant, exact math).
//
// amdgpu_waves_per_eu(1,1): the grid is 512 single-wave blocks (2/CU) --
// occupancy is grid-limited, so target 1 wave/EU and give the allocator the
// full VGPR file. Round 3/4 evidence: without this the allocator packs the
// kernel into 32 VGPRs and spends ~half of all dynamic VALU instructions on
// AGPR-copy/remat of etcol[] (measured 611 cyc/step, ~156 inst/step issued
// vs ~75 in source). __launch_bounds__(64,1) alone did NOT lift it (caps,
// doesn't target).
// ---------------------------------------------------------------------------
__global__ __launch_bounds__(WAVE)
__attribute__((amdgpu_waves_per_eu(1, 1)))
void crf_scan_kernel(
    const float* __restrict__ emissions, const int* __restrict__ mask,
    const float* __restrict__ transitions, const float* __restrict__ start_t,
    const float* __restrict__ end_t, const float* __restrict__ tmask,
    const float* __restrict__ smask, const float* __restrict__ emask,
    float* __restrict__ logz_out, int T) {
  const int b = blockIdx.x;
  const int j = threadIdx.x;

  __shared__ float s_trans[CC * CC];
  for (int k = j; k < CC * CC; k += WAVE) s_trans[k] = transitions[k] + tmask[k];
  __syncthreads();

  // lane j holds exp(trans[i][j]) for all i (column j); lanes >= CC hold 0.
  float etcol[CC];
#pragma unroll
  for (int i = 0; i < CC; ++i)
    etcol[i] = (j < CC) ? __expf(s_trans[i * CC + j]) : 0.0f;

  const float* __restrict__ emb = emissions + (size_t)b * T * CC;
  const int* __restrict__ maskb = mask + (size_t)b * T;

  const float NEG = -INFINITY;
  // p = exp(alpha0); lanes >= CC stay exactly 0 forever.
  float p = (j < CC) ? __expf(start_t[j] + smask[j] + emb[j]) : 0.0f;
  float logoff = 0.0f;

  // prefetch ring: raw emission + mask for steps t0..t0+PF-1
  float em_pre[PF];
  int mc[PF];
#pragma unroll
  for (int k = 0; k < PF; ++k) {
    int t = 1 + k;
    int tc = t < T ? t : T - 1;
    em_pre[k] = (j < CC) ? emb[(size_t)tc * CC + j] : NEG;
    mc[k] = maskb[tc];
  }

  int t0 = 1;
  for (; t0 + PF <= T; t0 += PF) {
#pragma unroll
    for (int k = 0; k < PF; ++k) {
      float emk = em_pre[k];
      int mt = mc[k];
      // issue prefetch for t0+PF+k (consumed 8 steps later)
      {
        int tn = t0 + PF + k;
        int tc = tn < T ? tn : T - 1;
        em_pre[k] = (j < CC) ? emb[(size_t)tc * CC + j] : NEG;
        mc[k] = maskb[tc];
      }
      float eemk = __expf(emk);  // off the p-chain (dep: 8-steps-old load)

      // dot: s_j = sum_i p_i * etcol[i], broadcast via readlane
      float a0 = 0.f, a1 = 0.f, a2 = 0.f, a3 = 0.f;
#pragma unroll
      for (int i = 0; i < 32; i += 4) {
        a0 = fmaf(rl(p, i + 0), etcol[i + 0], a0);
        a1 = fmaf(rl(p, i + 1), etcol[i + 1], a1);
        a2 = fmaf(rl(p, i + 2), etcol[i + 2], a2);
        a3 = fmaf(rl(p, i + 3), etcol[i + 3], a3);
      }
      float s = ((a0 + a1) + (a2 + a3)) + rl(p, 32) * etcol[32];

      if ((k & 3) == 0) {
        // renormalize by previous p[0] (uniform), fold into the emission mul
        float r = rl(p, 0);
        float rs = __builtin_amdgcn_rcpf(r);
        float pn = s * (eemk * rs);
        p = mt ? pn : p;
        logoff += mt ? __logf(r) : 0.0f;
      } else {
        float pn = s * eemk;
        p = mt ? pn : p;
      }
    }
  }
  // tail (< PF steps), fully unrolled so slot indices stay compile-time
#pragma unroll
  for (int k = 0; k < PF; ++k) {
    if (t0 + k < T) {
      float emk = em_pre[k];
      int mt = mc[k];
      float eemk = __expf(emk);
      float a0 = 0.f, a1 = 0.f, a2 = 0.f, a3 = 0.f;
#pragma unroll
      for (int i = 0; i < 32; i += 4) {
        a0 = fmaf(rl(p, i + 0), etcol[i + 0], a0);
        a1 = fmaf(rl(p, i + 1), etcol[i + 1], a1);
        a2 = fmaf(rl(p, i + 2), etcol[i + 2], a2);
        a3 = fmaf(rl(p, i + 3), etcol[i + 3], a3);
      }
      float s = ((a0 + a1) + (a2 + a3)) + rl(p, 32) * etcol[32];
      if ((k & 3) == 0) {
        float r = rl(p, 0);
        float rs = __builtin_amdgcn_rcpf(r);
        float pn = s * (eemk * rs);
        p = mt ? pn : p;
        logoff += mt ? __logf(r) : 0.0f;
      } else {
        float pn = s * eemk;
        p = mt ? pn : p;
      }
    }
  }

  // log_z = logoff + log( sum_j p_j * exp(end_s_j) )
  float eend = (j < CC) ? __expf(end_t[j] + emask[j]) : 0.0f;
  float sum = wave_sum64(p * eend);
  if (j == 0) logz_out[b] = logoff + __logf(sum);
}

// ---------------------------------------------------------------------------
// Gold-path score: embarrassingly parallel over (b, t).
// ---------------------------------------------------------------------------
__global__ __launch_bounds__(256) void crf_score_kernel(
    const float* __restrict__ emissions, const int* __restrict__ tags,
    const int* __restrict__ mask, const float* __restrict__ transitions,
    const float* __restrict__ start_t, const float* __restrict__ end_t,
    const float* __restrict__ tmask, const float* __restrict__ smask,
    const float* __restrict__ emask, float* __restrict__ score_out, int T) {
  const int b = blockIdx.x;
  const int tid = threadIdx.x;

  __shared__ float s_trans[CC * CC];
  for (int k = tid; k < CC * CC; k += 256) s_trans[k] = transitions[k] + tmask[k];
  __syncthreads();

  const float* __restrict__ emb = emissions + (size_t)b * T * CC;
  const int* __restrict__ tagb = tags + (size_t)b * T;
  const int* __restrict__ maskb = mask + (size_t)b * T;

  float local = 0.f;
  int llen = 0;
  for (int t = tid; t < T; t += 256) {
    int mt = maskb[t];
    llen += (mt != 0);
    if (t >= 1) {
      int cur = tagb[t];
      int prev = tagb[t - 1];
      float v = s_trans[prev * CC + cur] + emb[(size_t)t * CC + cur];
      local += (mt != 0) ? v : 0.f;
    }
  }

  local = wave_sum64(local);
  llen = wave_isum64(llen);
  __shared__ float ws[4];
  __shared__ int wl[4];
  if ((tid & 63) == 0) { ws[tid >> 6] = local; wl[tid >> 6] = llen; }
  __syncthreads();
  if (tid == 0) {
    float total = ws[0] + ws[1] + ws[2] + ws[3];
    int len = wl[0] + wl[1] + wl[2] + wl[3];
    int tag0 = tagb[0];
    total += start_t[tag0] + smask[tag0] + emb[tag0];
    if (len < 1) len = 1;
    int last = tagb[len - 1];
    total += end_t[last] + emask[last];
    score_out[b] = total;
  }
}

__global__ __launch_bounds__(256) void reduce_mean_kernel(
    const float* __restrict__ logz, const float* __restrict__ score,
    float* __restrict__ out, int n) {
  int tid = threadIdx.x;
  float s = 0.f;
  for (int i = tid; i < n; i += 256) s += logz[i] - score[i];
  s = wave_sum64(s);
  __shared__ float ws[4];
  if ((tid & 63) == 0) ws[tid >> 6] = s;
  __syncthreads();
  if (tid == 0) out[0] = (ws[0] + ws[1] + ws[2] + ws[3]) / (float)n;
}

extern "C" void kernel_launch(void* const* d_in, const int* in_sizes, int n_in,
                              void* d_out, int out_size, void* d_ws, size_t ws_size,
                              hipStream_t stream) {
  const float* emissions = (const float*)d_in[0];
  const int* tags = (const int*)d_in[1];
  const int* mask = (const int*)d_in[2];
  const float* transitions = (const float*)d_in[3];
  const float* start_t = (const float*)d_in[4];
  const float* end_t = (const float*)d_in[5];
  const float* tmask = (const float*)d_in[6];
  const float* smask = (const float*)d_in[7];
  const float* emask = (const float*)d_in[8];

  const int T = 2048;          // fixed problem shape
  const int BT = in_sizes[1];  // B*T
  const int B = BT / T;

  float* logz = (float*)d_ws;       // B floats
  float* score = logz + B;          // B floats

  crf_scan_kernel<<<B, WAVE, 0, stream>>>(emissions, mask, transitions, start_t,
                                          end_t, tmask, smask, emask, logz, T);
  crf_score_kernel<<<B, 256, 0, stream>>>(emissions, tags, mask, transitions,
                                          start_t, end_t, tmask, smask, emask,
                                          score, T);
  reduce_mean_kernel<<<1, 256, 0, stream>>>(logz, score, (float*)d_out, B);
}

// Round 6
// 248.397 us; speedup vs baseline: 1.9378x; 1.9357x over previous
//
#include <hip/hip_runtime.h>

#define CC 33
#define WAVE 64

__device__ __forceinline__ float wave_sum64(float v) {
#pragma unroll
  for (int k = 32; k >= 1; k >>= 1) v += __shfl_xor(v, k, 64);
  return v;
}

__device__ __forceinline__ int wave_isum64(int v) {
#pragma unroll
  for (int k = 32; k >= 1; k >>= 1) v += __shfl_xor(v, k, 64);
  return v;
}

__device__ __forceinline__ float rl(float v, int lane) {
  return __uint_as_float(__builtin_amdgcn_readlane(__float_as_uint(v), lane));
}

// 33-term broadcast dot: s = sum_i rl(u,i) * etv[i]; 8 accumulators (depth 4).
__device__ __forceinline__ float bdot33(float u, const float* etv) {
  float a0 = 0.f, a1 = 0.f, a2 = 0.f, a3 = 0.f;
  float a4 = 0.f, a5 = 0.f, a6 = 0.f, a7 = 0.f;
#pragma unroll
  for (int i = 0; i < 32; i += 8) {
    a0 = fmaf(rl(u, i + 0), etv[i + 0], a0);
    a1 = fmaf(rl(u, i + 1), etv[i + 1], a1);
    a2 = fmaf(rl(u, i + 2), etv[i + 2], a2);
    a3 = fmaf(rl(u, i + 3), etv[i + 3], a3);
    a4 = fmaf(rl(u, i + 4), etv[i + 4], a4);
    a5 = fmaf(rl(u, i + 5), etv[i + 5], a5);
    a6 = fmaf(rl(u, i + 6), etv[i + 6], a6);
    a7 = fmaf(rl(u, i + 7), etv[i + 7], a7);
  }
  a0 = fmaf(rl(u, 32), etv[32], a0);
  return (((a0 + a1) + (a2 + a3)) + ((a4 + a5) + (a6 + a7)));
}

// ---------------------------------------------------------------------------
// Pack mask[b][t] (int) into bit-words: packed[b][w] bit l = mask[b][w*64+l].
// Removes all per-step mask memory traffic from the scan's hot loop.
// ---------------------------------------------------------------------------
__global__ __launch_bounds__(WAVE) void pack_mask_kernel(
    const int* __restrict__ mask, unsigned long long* __restrict__ packed,
    int T) {
  const int b = blockIdx.x;
  const int l = threadIdx.x;
  const int* mb = mask + (size_t)b * T;
  const int W = T / 64;
  for (int w = 0; w < W; ++w) {
    unsigned long long bal = __ballot(mb[w * 64 + l] != 0);
    if (l == 0) packed[(size_t)b * W + w] = bal;
  }
}

// ---------------------------------------------------------------------------
// Half-scan: block bid<B runs FORWARD alpha over t=1..TM-1; block B+bid runs
// BACKWARD beta over t=T-1..TM. Exact stitch: logZ = lse(alpha_TM-1+beta_TM-1)
// (masked steps carry both recurrences, so the invariant holds for any mask).
// Linear space with renorm by p[0] every 4 steps; log accumulated in logoff.
// Hot loop vmem = em ring only (8 deep); masks are SALU bit-extracts from a
// scalar word prefetched one 64-step window ahead.
// ---------------------------------------------------------------------------
template <bool FWD>
__device__ __forceinline__ void half_scan(
    const float* __restrict__ emb, const unsigned long long* __restrict__ pkb,
    const float* __restrict__ etv, int jj, int j, float& p, float& logoff,
    int T, int TM) {
  const int W = T / 64;
  unsigned long long mw_cur = 0ull, mw_next;

  if (FWD) {
    mw_cur = pkb[0];
    mw_next = pkb[1];
  } else {
    mw_next = pkb[W - 1];
  }

  // ring prologue: first macro's emissions
  float em_pre[8];
#pragma unroll
  for (int k = 0; k < 8; ++k) {
    int tp = FWD ? (8 + k) : (T - 1 - k);
    em_pre[k] = emb[(size_t)tp * CC + jj];
  }

  if (FWD) {
    // pre-steps t=1..7 (unaligned head), direct loads
    float em7[7];
#pragma unroll
    for (int t = 1; t < 8; ++t) em7[t - 1] = emb[(size_t)t * CC + jj];
#pragma unroll
    for (int t = 1; t < 8; ++t) {
      float eem = __expf(em7[t - 1]);
      float s = bdot33(p, etv);
      int mt = (int)((mw_cur >> t) & 1ull);
      float pn = s * eem;
      p = mt ? pn : p;
    }
  }

  const int NM = FWD ? (TM - 8) / 8 : (T - TM) / 8;  // 127 / 128 macros
  int t0 = FWD ? 8 : T - 1;

  for (int mm = 0; mm < NM; ++mm) {
    // refresh the 64-step mask window (scalar; prefetched a window ahead)
    if (FWD ? ((t0 & 63) == 0) : ((t0 & 63) == 63)) {
      mw_cur = mw_next;
      int wn = (t0 >> 6) + (FWD ? 1 : -1);
      wn = wn < 0 ? 0 : (wn >= W ? W - 1 : wn);
      mw_next = pkb[wn];
    }
    int mbit[8];
#pragma unroll
    for (int k = 0; k < 8; ++k) {
      int t = FWD ? (t0 + k) : (t0 - k);
      mbit[k] = (int)((mw_cur >> (t & 63)) & 1ull);
    }
#pragma unroll
    for (int k = 0; k < 8; ++k) {
      float emk = em_pre[k];
      int mt = mbit[k];
      {  // refill ring slot for next macro
        int tp = FWD ? (t0 + 8 + k) : (t0 - 8 - k);
        tp = tp < 0 ? 0 : (tp > T - 1 ? T - 1 : tp);
        em_pre[k] = emb[(size_t)tp * CC + jj];
      }
      float eemk = __expf(emk);
      float pn;
      if ((k & 3) == 0) {
        float r = rl(p, 0);
        float rs = __builtin_amdgcn_rcpf(r);
        if (FWD) {
          float s = bdot33(p, etv);
          pn = s * (eemk * rs);
        } else {
          float u = p * (eemk * rs);
          pn = bdot33(u, etv);
        }
        p = mt ? pn : p;
        logoff += mt ? __logf(r) : 0.f;
      } else {
        if (FWD) {
          float s = bdot33(p, etv);
          pn = s * eemk;
        } else {
          float u = p * eemk;
          pn = bdot33(u, etv);
        }
        p = mt ? pn : p;
      }
    }
    t0 += FWD ? 8 : -8;
  }
}

__global__ __launch_bounds__(WAVE)
__attribute__((amdgpu_waves_per_eu(1, 1)))
void crf_halfscan_kernel(
    const float* __restrict__ emissions,
    const unsigned long long* __restrict__ pmask,
    const float* __restrict__ transitions, const float* __restrict__ start_t,
    const float* __restrict__ end_t, const float* __restrict__ tmask,
    const float* __restrict__ smask, const float* __restrict__ emask,
    float* __restrict__ pvec_out, float* __restrict__ logoff_out, int T, int B,
    int TM) {
  const int bid = blockIdx.x;
  const bool fwd = bid < B;
  const int b = fwd ? bid : bid - B;
  const int j = threadIdx.x;
  const int jj = (j < CC) ? j : 0;

  __shared__ float s_trans[CC * CC];
  for (int k = j; k < CC * CC; k += WAVE) s_trans[k] = transitions[k] + tmask[k];
  __syncthreads();

  // fwd: lane j holds ET column j (broadcast over source state i)
  // bwd: lane j holds ET row j    (broadcast over target state i)
  float etv[CC];
#pragma unroll
  for (int i = 0; i < CC; ++i) {
    float tv = fwd ? s_trans[i * CC + jj] : s_trans[jj * CC + i];
    etv[i] = (j < CC) ? __expf(tv) : 0.f;
  }

  const float* emb = emissions + (size_t)b * T * CC;
  const unsigned long long* pkb = pmask + (size_t)b * (T / 64);

  float p, logoff = 0.f;
  if (fwd) {
    p = (j < CC) ? __expf(start_t[jj] + smask[jj] + emb[jj]) : 0.f;
    half_scan<true>(emb, pkb, etv, jj, j, p, logoff, T, TM);
  } else {
    p = (j < CC) ? __expf(end_t[jj] + emask[jj]) : 0.f;
    half_scan<false>(emb, pkb, etv, jj, j, p, logoff, T, TM);
  }

  pvec_out[(size_t)bid * WAVE + j] = p;
  if (j == 0) logoff_out[bid] = logoff;
}

// ---------------------------------------------------------------------------
// Gold-path score: embarrassingly parallel over (b, t).
// ---------------------------------------------------------------------------
__global__ __launch_bounds__(256) void crf_score_kernel(
    const float* __restrict__ emissions, const int* __restrict__ tags,
    const int* __restrict__ mask, const float* __restrict__ transitions,
    const float* __restrict__ start_t, const float* __restrict__ end_t,
    const float* __restrict__ tmask, const float* __restrict__ smask,
    const float* __restrict__ emask, float* __restrict__ score_out, int T) {
  const int b = blockIdx.x;
  const int tid = threadIdx.x;

  __shared__ float s_trans[CC * CC];
  for (int k = tid; k < CC * CC; k += 256) s_trans[k] = transitions[k] + tmask[k];
  __syncthreads();

  const float* __restrict__ emb = emissions + (size_t)b * T * CC;
  const int* __restrict__ tagb = tags + (size_t)b * T;
  const int* __restrict__ maskb = mask + (size_t)b * T;

  float local = 0.f;
  int llen = 0;
  for (int t = tid; t < T; t += 256) {
    int mt = maskb[t];
    llen += (mt != 0);
    if (t >= 1) {
      int cur = tagb[t];
      int prev = tagb[t - 1];
      float v = s_trans[prev * CC + cur] + emb[(size_t)t * CC + cur];
      local += (mt != 0) ? v : 0.f;
    }
  }

  local = wave_sum64(local);
  llen = wave_isum64(llen);
  __shared__ float ws[4];
  __shared__ int wl[4];
  if ((tid & 63) == 0) { ws[tid >> 6] = local; wl[tid >> 6] = llen; }
  __syncthreads();
  if (tid == 0) {
    float total = ws[0] + ws[1] + ws[2] + ws[3];
    int len = wl[0] + wl[1] + wl[2] + wl[3];
    int tag0 = tagb[0];
    total += start_t[tag0] + smask[tag0] + emb[tag0];
    if (len < 1) len = 1;
    int last = tagb[len - 1];
    total += end_t[last] + emask[last];
    score_out[b] = total;
  }
}

// nll[b] = logoffF + logoffB + log(sum_j pF_j * pB_j) - score[b]
__global__ __launch_bounds__(WAVE) void crf_combine_kernel(
    const float* __restrict__ pvec, const float* __restrict__ logoffs,
    const float* __restrict__ score, float* __restrict__ nll, int B) {
  const int b = blockIdx.x;
  const int j = threadIdx.x;
  float pf = pvec[(size_t)b * WAVE + j];
  float pb = pvec[(size_t)(B + b) * WAVE + j];
  float s = wave_sum64(pf * pb);
  if (j == 0) nll[b] = logoffs[b] + logoffs[B + b] + __logf(s) - score[b];
}

__global__ __launch_bounds__(256) void reduce_mean_kernel(
    const float* __restrict__ nll, float* __restrict__ out, int n) {
  int tid = threadIdx.x;
  float s = 0.f;
  for (int i = tid; i < n; i += 256) s += nll[i];
  s = wave_sum64(s);
  __shared__ float ws[4];
  if ((tid & 63) == 0) ws[tid >> 6] = s;
  __syncthreads();
  if (tid == 0) out[0] = (ws[0] + ws[1] + ws[2] + ws[3]) / (float)n;
}

extern "C" void kernel_launch(void* const* d_in, const int* in_sizes, int n_in,
                              void* d_out, int out_size, void* d_ws, size_t ws_size,
                              hipStream_t stream) {
  const float* emissions = (const float*)d_in[0];
  const int* tags = (const int*)d_in[1];
  const int* mask = (const int*)d_in[2];
  const float* transitions = (const float*)d_in[3];
  const float* start_t = (const float*)d_in[4];
  const float* end_t = (const float*)d_in[5];
  const float* tmask = (const float*)d_in[6];
  const float* smask = (const float*)d_in[7];
  const float* emask = (const float*)d_in[8];

  const int T = 2048;          // fixed problem shape
  const int TM = T / 2;        // fwd/bwd meet point
  const int BT = in_sizes[1];  // B*T
  const int B = BT / T;
  const int W = T / 64;

  char* ws = (char*)d_ws;
  unsigned long long* packed = (unsigned long long*)ws;          // B*W u64
  float* pvec = (float*)(ws + (size_t)B * W * 8);                // 2B*64 f
  float* logoffs = pvec + (size_t)2 * B * WAVE;                  // 2B f
  float* score = logoffs + (size_t)2 * B;                        // B f
  float* nll = score + B;                                        // B f

  pack_mask_kernel<<<B, WAVE, 0, stream>>>(mask, packed, T);
  crf_halfscan_kernel<<<2 * B, WAVE, 0, stream>>>(
      emissions, packed, transitions, start_t, end_t, tmask, smask, emask,
      pvec, logoffs, T, B, TM);
  crf_score_kernel<<<B, 256, 0, stream>>>(emissions, tags, mask, transitions,
                                          start_t, end_t, tmask, smask, emask,
                                          score, T);
  crf_combine_kernel<<<B, WAVE, 0, stream>>>(pvec, logoffs, score, nll, B);
  reduce_mean_kernel<<<1, 256, 0, stream>>>(nll, (float*)d_out, B);
}

// Round 7
// 239.625 us; speedup vs baseline: 2.0087x; 1.0366x over previous
//
#include <hip/hip_runtime.h>

#define CC 33
#define WAVE 64
#define BURN 64

__device__ __forceinline__ float wave_sum64(float v) {
#pragma unroll
  for (int k = 32; k >= 1; k >>= 1) v += __shfl_xor(v, k, 64);
  return v;
}

__device__ __forceinline__ int wave_isum64(int v) {
#pragma unroll
  for (int k = 32; k >= 1; k >>= 1) v += __shfl_xor(v, k, 64);
  return v;
}

__device__ __forceinline__ float rl(float v, int lane) {
  return __uint_as_float(__builtin_amdgcn_readlane(__float_as_uint(v), lane));
}

// 33-term broadcast dot: s = sum_i rl(u,i) * etv[i]; 8 accumulators (depth 4).
__device__ __forceinline__ float bdot33(float u, const float* etv) {
  float a0 = 0.f, a1 = 0.f, a2 = 0.f, a3 = 0.f;
  float a4 = 0.f, a5 = 0.f, a6 = 0.f, a7 = 0.f;
#pragma unroll
  for (int i = 0; i < 32; i += 8) {
    a0 = fmaf(rl(u, i + 0), etv[i + 0], a0);
    a1 = fmaf(rl(u, i + 1), etv[i + 1], a1);
    a2 = fmaf(rl(u, i + 2), etv[i + 2], a2);
    a3 = fmaf(rl(u, i + 3), etv[i + 3], a3);
    a4 = fmaf(rl(u, i + 4), etv[i + 4], a4);
    a5 = fmaf(rl(u, i + 5), etv[i + 5], a5);
    a6 = fmaf(rl(u, i + 6), etv[i + 6], a6);
    a7 = fmaf(rl(u, i + 7), etv[i + 7], a7);
  }
  a0 = fmaf(rl(u, 32), etv[32], a0);
  return (((a0 + a1) + (a2 + a3)) + ((a4 + a5) + (a6 + a7)));
}

// ---------------------------------------------------------------------------
// Pack mask[b][t] (int) into bit-words: packed[b][w] bit l = mask[b][w*64+l].
// ---------------------------------------------------------------------------
__global__ __launch_bounds__(WAVE) void pack_mask_kernel(
    const int* __restrict__ mask, unsigned long long* __restrict__ packed,
    int T) {
  const int b = blockIdx.x;
  const int l = threadIdx.x;
  const int* mb = mask + (size_t)b * T;
  const int W = T / 64;
  for (int w = 0; w < W; ++w) {
    unsigned long long bal = __ballot(mb[w * 64 + l] != 0);
    if (l == 0) packed[(size_t)b * W + w] = bal;
  }
}

// ---------------------------------------------------------------------------
// Chunked forward scan with burn-in. Chunk c owns transition steps
// t in [c*S+1, min((c+1)*S, T-1)]. Chunks c>0 start 64 steps early (burn-in)
// from the uniform vector: the normalized direction q converges to the true
// one at the Birkhoff contraction rate (~0.8^64 ~ 1e-7 for exp(N(0,1))
// transitions); masked steps are identity for both chains so the invariant
// survives any mask pattern. Contribution of a chunk is the telescoping
// difference of L = logoff + log(sum p) across its own range (burn-in logoff
// cancels in the difference). Chunk 0 starts exact (contains initial mass);
// the last chunk dots with exp(end scores) for its L_end.
// Linear-space recurrence with p[0]-renorm every 4 steps, as validated in R6.
// __launch_bounds__(64,4): 16 blocks/CU -> 4 waves/SIMD needs VGPR<=128
// (R4/R5 showed VGPR squeeze is perf-neutral; stalls dominate, not remat).
// ---------------------------------------------------------------------------
__global__ __launch_bounds__(WAVE, 4) void crf_chunk_kernel(
    const float* __restrict__ emissions,
    const unsigned long long* __restrict__ pmask,
    const float* __restrict__ transitions, const float* __restrict__ start_t,
    const float* __restrict__ end_t, const float* __restrict__ tmask,
    const float* __restrict__ smask, const float* __restrict__ emask,
    float* __restrict__ contrib, int T, int B, int S, int K) {
  const int bid = blockIdx.x;
  const int c = bid / B;
  const int b = bid - c * B;
  const int j = threadIdx.x;
  const int jj = (j < CC) ? j : 0;
  const int W = T / 64;

  __shared__ float s_trans[CC * CC];
  for (int k = j; k < CC * CC; k += WAVE) s_trans[k] = transitions[k] + tmask[k];
  __syncthreads();

  // lane j holds exp(trans[i][j]) (column j); lanes >= CC hold 0.
  float etv[CC];
#pragma unroll
  for (int i = 0; i < CC; ++i)
    etv[i] = (j < CC) ? __expf(s_trans[i * CC + jj]) : 0.f;

  const float* __restrict__ emb = emissions + (size_t)b * T * CC;
  const unsigned long long* __restrict__ pkb = pmask + (size_t)b * W;

  const int t_end = ((c + 1) * S < T - 1) ? (c + 1) * S : (T - 1);
  const int t_begin = (c == 0) ? 1 : c * S - (BURN - 1);
  const int NM = (c == 0) ? S / 8 : (S + BURN) / 8;

  float p, logoff = 0.f, Lstart = 0.f;
  if (c == 0) {
    p = (j < CC) ? __expf(start_t[jj] + smask[jj] + emb[jj]) : 0.f;
  } else {
    p = (j < CC) ? 1.0f : 0.f;
  }

  // mask windows (wave-uniform scalar words)
  int wcur = t_begin >> 6;
  unsigned long long mw0 = pkb[wcur];
  int wn1 = (wcur + 1 < W) ? wcur + 1 : W - 1;
  unsigned long long mw1 = pkb[wn1];

  // emission ring: depth 8 (one macro ahead)
  float em_pre[8];
#pragma unroll
  for (int k = 0; k < 8; ++k) {
    int tp = t_begin + k;
    tp = tp > T - 1 ? T - 1 : tp;
    em_pre[k] = emb[(size_t)tp * CC + jj];
  }

  int t0 = t_begin;
  for (int mm = 0; mm < NM; ++mm) {
    int w = t0 >> 6;
    if (w != wcur) {
      mw0 = mw1;
      wcur = w;
      int wn = (w + 1 < W) ? w + 1 : W - 1;
      mw1 = pkb[wn];
    }
    int mbit[8];
#pragma unroll
    for (int k = 0; k < 8; ++k) {
      int t = t0 + k;
      unsigned long long mw = ((t >> 6) == wcur) ? mw0 : mw1;
      mbit[k] = (int)((mw >> (t & 63)) & 1ull) & (t <= t_end ? 1 : 0);
    }
#pragma unroll
    for (int k = 0; k < 8; ++k) {
      float emk = em_pre[k];
      int mt = mbit[k];
      {  // refill ring slot for next macro
        int tp = t0 + 8 + k;
        tp = tp > T - 1 ? T - 1 : tp;
        em_pre[k] = emb[(size_t)tp * CC + jj];
      }
      float eemk = __expf(emk);
      float s = bdot33(p, etv);
      if ((k & 3) == 0) {
        float r = rl(p, 0);
        float rs = __builtin_amdgcn_rcpf(r);
        float pn = s * (eemk * rs);
        p = mt ? pn : p;
        logoff += mt ? __logf(r) : 0.f;
      } else {
        float pn = s * eemk;
        p = mt ? pn : p;
      }
    }
    t0 += 8;
    if (c > 0 && mm == (BURN / 8 - 1)) {
      // end of burn-in: snapshot L at t = c*S
      Lstart = logoff + __logf(wave_sum64(p));
    }
  }

  float Lend;
  if (c == K - 1) {
    float eendv = (j < CC) ? __expf(end_t[jj] + emask[jj]) : 0.f;
    Lend = logoff + __logf(wave_sum64(p * eendv));
  } else {
    Lend = logoff + __logf(wave_sum64(p));
  }
  if (j == 0) contrib[(size_t)c * B + b] = Lend - Lstart;
}

// ---------------------------------------------------------------------------
// Gold-path score: embarrassingly parallel over (b, t).
// ---------------------------------------------------------------------------
__global__ __launch_bounds__(256) void crf_score_kernel(
    const float* __restrict__ emissions, const int* __restrict__ tags,
    const int* __restrict__ mask, const float* __restrict__ transitions,
    const float* __restrict__ start_t, const float* __restrict__ end_t,
    const float* __restrict__ tmask, const float* __restrict__ smask,
    const float* __restrict__ emask, float* __restrict__ score_out, int T) {
  const int b = blockIdx.x;
  const int tid = threadIdx.x;

  __shared__ float s_trans[CC * CC];
  for (int k = tid; k < CC * CC; k += 256) s_trans[k] = transitions[k] + tmask[k];
  __syncthreads();

  const float* __restrict__ emb = emissions + (size_t)b * T * CC;
  const int* __restrict__ tagb = tags + (size_t)b * T;
  const int* __restrict__ maskb = mask + (size_t)b * T;

  float local = 0.f;
  int llen = 0;
  for (int t = tid; t < T; t += 256) {
    int mt = maskb[t];
    llen += (mt != 0);
    if (t >= 1) {
      int cur = tagb[t];
      int prev = tagb[t - 1];
      float v = s_trans[prev * CC + cur] + emb[(size_t)t * CC + cur];
      local += (mt != 0) ? v : 0.f;
    }
  }

  local = wave_sum64(local);
  llen = wave_isum64(llen);
  __shared__ float ws[4];
  __shared__ int wl[4];
  if ((tid & 63) == 0) { ws[tid >> 6] = local; wl[tid >> 6] = llen; }
  __syncthreads();
  if (tid == 0) {
    float total = ws[0] + ws[1] + ws[2] + ws[3];
    int len = wl[0] + wl[1] + wl[2] + wl[3];
    int tag0 = tagb[0];
    total += start_t[tag0] + smask[tag0] + emb[tag0];
    if (len < 1) len = 1;
    int last = tagb[len - 1];
    total += end_t[last] + emask[last];
    score_out[b] = total;
  }
}

// out = mean_b( sum_c contrib[c][b] - score[b] )
__global__ __launch_bounds__(512) void crf_finish_kernel(
    const float* __restrict__ contrib, const float* __restrict__ score,
    float* __restrict__ out, int B, int K) {
  const int b = threadIdx.x;  // one thread per sequence (B == 512)
  float v = 0.f;
  if (b < B) {
    for (int c = 0; c < K; ++c) v += contrib[(size_t)c * B + b];
    v -= score[b];
  }
  v = wave_sum64(v);
  __shared__ float ws[8];
  if ((b & 63) == 0) ws[b >> 6] = v;
  __syncthreads();
  if (b == 0) {
    float s = 0.f;
    for (int q = 0; q < 8; ++q) s += ws[q];
    out[0] = s / (float)B;
  }
}

extern "C" void kernel_launch(void* const* d_in, const int* in_sizes, int n_in,
                              void* d_out, int out_size, void* d_ws, size_t ws_size,
                              hipStream_t stream) {
  const float* emissions = (const float*)d_in[0];
  const int* tags = (const int*)d_in[1];
  const int* mask = (const int*)d_in[2];
  const float* transitions = (const float*)d_in[3];
  const float* start_t = (const float*)d_in[4];
  const float* end_t = (const float*)d_in[5];
  const float* tmask = (const float*)d_in[6];
  const float* smask = (const float*)d_in[7];
  const float* emask = (const float*)d_in[8];

  const int T = 2048;          // fixed problem shape
  const int K = 8;             // chunks per sequence
  const int S = T / K;         // 256
  const int BT = in_sizes[1];  // B*T
  const int B = BT / T;
  const int W = T / 64;

  char* ws = (char*)d_ws;
  unsigned long long* packed = (unsigned long long*)ws;   // B*W u64
  float* contrib = (float*)(ws + (size_t)B * W * 8);      // K*B f
  float* score = contrib + (size_t)K * B;                 // B f

  pack_mask_kernel<<<B, WAVE, 0, stream>>>(mask, packed, T);
  crf_chunk_kernel<<<K * B, WAVE, 0, stream>>>(
      emissions, packed, transitions, start_t, end_t, tmask, smask, emask,
      contrib, T, B, S, K);
  crf_score_kernel<<<B, 256, 0, stream>>>(emissions, tags, mask, transitions,
                                          start_t, end_t, tmask, smask, emask,
                                          score, T);
  crf_finish_kernel<<<1, 512, 0, stream>>>(contrib, score, (float*)d_out, B, K);
}

// Round 12
// 236.811 us; speedup vs baseline: 2.0326x; 1.0119x over previous
//
#include <hip/hip_runtime.h>

#define CC 33
#define WAVE 64
#define BURN 64

__device__ __forceinline__ float wave_sum64(float v) {
#pragma unroll
  for (int k = 32; k >= 1; k >>= 1) v += __shfl_xor(v, k, 64);
  return v;
}

__device__ __forceinline__ int wave_isum64(int v) {
#pragma unroll
  for (int k = 32; k >= 1; k >>= 1) v += __shfl_xor(v, k, 64);
  return v;
}

__device__ __forceinline__ float rl(float v, int lane) {
  return __uint_as_float(__builtin_amdgcn_readlane(__float_as_uint(v), lane));
}

// 33-term broadcast dot: s = sum_i rl(u,i) * etv[i]; 8 accumulators (depth 4).
__device__ __forceinline__ float bdot33(float u, const float* etv) {
  float a0 = 0.f, a1 = 0.f, a2 = 0.f, a3 = 0.f;
  float a4 = 0.f, a5 = 0.f, a6 = 0.f, a7 = 0.f;
#pragma unroll
  for (int i = 0; i < 32; i += 8) {
    a0 = fmaf(rl(u, i + 0), etv[i + 0], a0);
    a1 = fmaf(rl(u, i + 1), etv[i + 1], a1);
    a2 = fmaf(rl(u, i + 2), etv[i + 2], a2);
    a3 = fmaf(rl(u, i + 3), etv[i + 3], a3);
    a4 = fmaf(rl(u, i + 4), etv[i + 4], a4);
    a5 = fmaf(rl(u, i + 5), etv[i + 5], a5);
    a6 = fmaf(rl(u, i + 6), etv[i + 6], a6);
    a7 = fmaf(rl(u, i + 7), etv[i + 7], a7);
  }
  a0 = fmaf(rl(u, 32), etv[32], a0);
  return (((a0 + a1) + (a2 + a3)) + ((a4 + a5) + (a6 + a7)));
}

// ---------------------------------------------------------------------------
// Pack mask[b][t] (int) into bit-words: packed[b][w] bit l = mask[b][w*64+l].
// ---------------------------------------------------------------------------
__global__ __launch_bounds__(WAVE) void pack_mask_kernel(
    const int* __restrict__ mask, unsigned long long* __restrict__ packed,
    int T) {
  const int b = blockIdx.x;
  const int l = threadIdx.x;
  const int* mb = mask + (size_t)b * T;
  const int W = T / 64;
  for (int w = 0; w < W; ++w) {
    unsigned long long bal = __ballot(mb[w * 64 + l] != 0);
    if (l == 0) packed[(size_t)b * W + w] = bal;
  }
}

// ---------------------------------------------------------------------------
// Chunked forward scan with burn-in (R7-proven structure, verbatim except the
// register-budget attribute).
//
// amdgpu_waves_per_eu(4,4): R7 ran this exact kernel with
// __launch_bounds__(64,4) and the allocator squeezed it to VGPR_Count=36 --
// etv[33] cannot live in 36 VGPRs, so the per-step dot reloaded it from
// scratch (~33 extra VMEM ops/step; measured 336 issue-cyc/step vs ~170 in
// source; R6 at VGPR=132 measured 296). waves_per_eu(4,4) keeps the same
// 4-waves/EU occupancy target but tells the allocator to use the 128-VGPR
// tier, putting etv/ring in registers (R5 precedent: waves_per_eu lifts
// allocation where __launch_bounds__ does not).
// ---------------------------------------------------------------------------
__global__ __launch_bounds__(WAVE)
__attribute__((amdgpu_waves_per_eu(4, 4)))
void crf_chunk_kernel(
    const float* __restrict__ emissions,
    const unsigned long long* __restrict__ pmask,
    const float* __restrict__ transitions, const float* __restrict__ start_t,
    const float* __restrict__ end_t, const float* __restrict__ tmask,
    const float* __restrict__ smask, const float* __restrict__ emask,
    float* __restrict__ contrib, int T, int B, int S, int K) {
  const int bid = blockIdx.x;
  const int c = bid / B;
  const int b = bid - c * B;
  const int j = threadIdx.x;
  const int jj = (j < CC) ? j : 0;
  const int W = T / 64;

  __shared__ float s_trans[CC * CC];
  for (int k = j; k < CC * CC; k += WAVE) s_trans[k] = transitions[k] + tmask[k];
  __syncthreads();

  float etv[CC];
#pragma unroll
  for (int i = 0; i < CC; ++i)
    etv[i] = (j < CC) ? __expf(s_trans[i * CC + jj]) : 0.f;

  const float* __restrict__ emb = emissions + (size_t)b * T * CC;
  const unsigned long long* __restrict__ pkb = pmask + (size_t)b * W;

  const int t_end = ((c + 1) * S < T - 1) ? (c + 1) * S : (T - 1);
  const int t_begin = (c == 0) ? 1 : c * S - (BURN - 1);
  const int NM = (c == 0) ? S / 8 : (S + BURN) / 8;

  float p, logoff = 0.f, Lstart = 0.f;
  if (c == 0) {
    p = (j < CC) ? __expf(start_t[jj] + smask[jj] + emb[jj]) : 0.f;
  } else {
    p = (j < CC) ? 1.0f : 0.f;
  }

  int wcur = t_begin >> 6;
  unsigned long long mw0 = pkb[wcur];
  int wn1 = (wcur + 1 < W) ? wcur + 1 : W - 1;
  unsigned long long mw1 = pkb[wn1];

  float em_pre[8];
#pragma unroll
  for (int k = 0; k < 8; ++k) {
    int tp = t_begin + k;
    tp = tp > T - 1 ? T - 1 : tp;
    em_pre[k] = emb[(size_t)tp * CC + jj];
  }

  int t0 = t_begin;
  for (int mm = 0; mm < NM; ++mm) {
    int w = t0 >> 6;
    if (w != wcur) {
      mw0 = mw1;
      wcur = w;
      int wn = (w + 1 < W) ? w + 1 : W - 1;
      mw1 = pkb[wn];
    }
    int mbit[8];
#pragma unroll
    for (int k = 0; k < 8; ++k) {
      int t = t0 + k;
      unsigned long long mw = ((t >> 6) == wcur) ? mw0 : mw1;
      mbit[k] = (int)((mw >> (t & 63)) & 1ull) & (t <= t_end ? 1 : 0);
    }
#pragma unroll
    for (int k = 0; k < 8; ++k) {
      float emk = em_pre[k];
      int mt = mbit[k];
      {
        int tp = t0 + 8 + k;
        tp = tp < 0 ? 0 : (tp > T - 1 ? T - 1 : tp);
        em_pre[k] = emb[(size_t)tp * CC + jj];
      }
      float eemk = __expf(emk);
      float s = bdot33(p, etv);
      if ((k & 3) == 0) {
        float r = rl(p, 0);
        float rs = __builtin_amdgcn_rcpf(r);
        float pn = s * (eemk * rs);
        p = mt ? pn : p;
        logoff += mt ? __logf(r) : 0.f;
      } else {
        float pn = s * eemk;
        p = mt ? pn : p;
      }
    }
    t0 += 8;
    if (c > 0 && mm == (BURN / 8 - 1)) {
      Lstart = logoff + __logf(wave_sum64(p));
    }
  }

  float Lend;
  if (c == K - 1) {
    float eendv = (j < CC) ? __expf(end_t[jj] + emask[jj]) : 0.f;
    Lend = logoff + __logf(wave_sum64(p * eendv));
  } else {
    Lend = logoff + __logf(wave_sum64(p));
  }
  if (j == 0) contrib[(size_t)c * B + b] = Lend - Lstart;
}

// ---------------------------------------------------------------------------
// Gold-path score: embarrassingly parallel over (b, t).  (R7-proven)
// ---------------------------------------------------------------------------
__global__ __launch_bounds__(256) void crf_score_kernel(
    const float* __restrict__ emissions, const int* __restrict__ tags,
    const int* __restrict__ mask, const float* __restrict__ transitions,
    const float* __restrict__ start_t, const float* __restrict__ end_t,
    const float* __restrict__ tmask, const float* __restrict__ smask,
    const float* __restrict__ emask, float* __restrict__ score_out, int T) {
  const int b = blockIdx.x;
  const int tid = threadIdx.x;

  __shared__ float s_trans[CC * CC];
  for (int k = tid; k < CC * CC; k += 256) s_trans[k] = transitions[k] + tmask[k];
  __syncthreads();

  const float* __restrict__ emb = emissions + (size_t)b * T * CC;
  const int* __restrict__ tagb = tags + (size_t)b * T;
  const int* __restrict__ maskb = mask + (size_t)b * T;

  float local = 0.f;
  int llen = 0;
  for (int t = tid; t < T; t += 256) {
    int mt = maskb[t];
    llen += (mt != 0);
    if (t >= 1) {
      int cur = tagb[t];
      int prev = tagb[t - 1];
      float v = s_trans[prev * CC + cur] + emb[(size_t)t * CC + cur];
      local += (mt != 0) ? v : 0.f;
    }
  }

  local = wave_sum64(local);
  llen = wave_isum64(llen);
  __shared__ float ws[4];
  __shared__ int wl[4];
  if ((tid & 63) == 0) { ws[tid >> 6] = local; wl[tid >> 6] = llen; }
  __syncthreads();
  if (tid == 0) {
    float total = ws[0] + ws[1] + ws[2] + ws[3];
    int len = wl[0] + wl[1] + wl[2] + wl[3];
    int tag0 = tagb[0];
    total += start_t[tag0] + smask[tag0] + emb[tag0];
    if (len < 1) len = 1;
    int last = tagb[len - 1];
    total += end_t[last] + emask[last];
    score_out[b] = total;
  }
}

// out = mean_b( sum_c contrib[c][b] - score[b] )
__global__ __launch_bounds__(512) void crf_finish_kernel(
    const float* __restrict__ contrib, const float* __restrict__ score,
    float* __restrict__ out, int B, int K) {
  const int b = threadIdx.x;  // one thread per sequence (B == 512)
  float v = 0.f;
  if (b < B) {
    for (int c = 0; c < K; ++c) v += contrib[(size_t)c * B + b];
    v -= score[b];
  }
  v = wave_sum64(v);
  __shared__ float ws[8];
  if ((b & 63) == 0) ws[b >> 6] = v;
  __syncthreads();
  if (b == 0) {
    float s = 0.f;
    for (int q = 0; q < 8; ++q) s += ws[q];
    out[0] = s / (float)B;
  }
}

extern "C" void kernel_launch(void* const* d_in, const int* in_sizes, int n_in,
                              void* d_out, int out_size, void* d_ws, size_t ws_size,
                              hipStream_t stream) {
  const float* emissions = (const float*)d_in[0];
  const int* tags = (const int*)d_in[1];
  const int* mask = (const int*)d_in[2];
  const float* transitions = (const float*)d_in[3];
  const float* start_t = (const float*)d_in[4];
  const float* end_t = (const float*)d_in[5];
  const float* tmask = (const float*)d_in[6];
  const float* smask = (const float*)d_in[7];
  const float* emask = (const float*)d_in[8];

  const int T = 2048;          // fixed problem shape
  const int K = 8;             // chunks per sequence
  const int S = T / K;         // 256
  const int BT = in_sizes[1];  // B*T
  const int B = BT / T;
  const int W = T / 64;

  char* ws = (char*)d_ws;
  unsigned long long* packed = (unsigned long long*)ws;   // B*W u64
  float* contrib = (float*)(ws + (size_t)B * W * 8);      // K*B f
  float* score = contrib + (size_t)K * B;                 // B f

  pack_mask_kernel<<<B, WAVE, 0, stream>>>(mask, packed, T);
  crf_chunk_kernel<<<K * B, WAVE, 0, stream>>>(
      emissions, packed, transitions, start_t, end_t, tmask, smask, emask,
      contrib, T, B, S, K);
  crf_score_kernel<<<B, 256, 0, stream>>>(emissions, tags, mask, transitions,
                                          start_t, end_t, tmask, smask, emask,
                                          score, T);
  crf_finish_kernel<<<1, 512, 0, stream>>>(contrib, score, (float*)d_out, B, K);
}

// Round 13
// 163.689 us; speedup vs baseline: 2.9406x; 1.4467x over previous
//
#include <hip/hip_runtime.h>

#define CC 33
#define WAVE 64
#define BURN 16

#if __has_builtin(__builtin_amdgcn_fdot2_f32_bf16)
#define HAS_BF16DOT 1
typedef __bf16 bfv2 __attribute__((ext_vector_type(2)));
#else
#define HAS_BF16DOT 0
#endif

__device__ __forceinline__ float wave_sum64(float v) {
#pragma unroll
  for (int k = 32; k >= 1; k >>= 1) v += __shfl_xor(v, k, 64);
  return v;
}

__device__ __forceinline__ int wave_isum64(int v) {
#pragma unroll
  for (int k = 32; k >= 1; k >>= 1) v += __shfl_xor(v, k, 64);
  return v;
}

__device__ __forceinline__ float rl(float v, int lane) {
  return __uint_as_float(__builtin_amdgcn_readlane(__float_as_uint(v), lane));
}

// f32 fallback dot: s = sum_i rl(u,i) * etv[i]; 8 accumulators.
__device__ __forceinline__ float bdot33(float u, const float* etv) {
  float a0 = 0.f, a1 = 0.f, a2 = 0.f, a3 = 0.f;
  float a4 = 0.f, a5 = 0.f, a6 = 0.f, a7 = 0.f;
#pragma unroll
  for (int i = 0; i < 32; i += 8) {
    a0 = fmaf(rl(u, i + 0), etv[i + 0], a0);
    a1 = fmaf(rl(u, i + 1), etv[i + 1], a1);
    a2 = fmaf(rl(u, i + 2), etv[i + 2], a2);
    a3 = fmaf(rl(u, i + 3), etv[i + 3], a3);
    a4 = fmaf(rl(u, i + 4), etv[i + 4], a4);
    a5 = fmaf(rl(u, i + 5), etv[i + 5], a5);
    a6 = fmaf(rl(u, i + 6), etv[i + 6], a6);
    a7 = fmaf(rl(u, i + 7), etv[i + 7], a7);
  }
  a0 = fmaf(rl(u, 32), etv[32], a0);
  return (((a0 + a1) + (a2 + a3)) + ((a4 + a5) + (a6 + a7)));
}

#if HAS_BF16DOT
__device__ __forceinline__ bfv2 rlpk(unsigned v, int lane) {
  return __builtin_bit_cast(
      bfv2, (unsigned)__builtin_amdgcn_readlane((int)v, lane));
}
// bf16 dot2 dot: ppk lane i = (bf16(p_i), bf16(p_{i+1})); etp[q] = lane-local
// (etv[2q], etv[2q+1]) pairs. 17 readlane + 17 v_dot2_f32_bf16, f32 accum.
__device__ __forceinline__ float bdot33_bf16(unsigned ppk, const bfv2* etp) {
  float a0 = 0.f, a1 = 0.f, a2 = 0.f, a3 = 0.f;
#pragma unroll
  for (int q = 0; q < 16; q += 4) {
    a0 = __builtin_amdgcn_fdot2_f32_bf16(rlpk(ppk, 2 * q + 0), etp[q + 0], a0, false);
    a1 = __builtin_amdgcn_fdot2_f32_bf16(rlpk(ppk, 2 * q + 2), etp[q + 1], a1, false);
    a2 = __builtin_amdgcn_fdot2_f32_bf16(rlpk(ppk, 2 * q + 4), etp[q + 2], a2, false);
    a3 = __builtin_amdgcn_fdot2_f32_bf16(rlpk(ppk, 2 * q + 6), etp[q + 3], a3, false);
  }
  a0 = __builtin_amdgcn_fdot2_f32_bf16(rlpk(ppk, 32), etp[16], a0, false);
  return (a0 + a1) + (a2 + a3);
}
#endif

// ---------------------------------------------------------------------------
// Pack mask[b][t] (int) into bit-words.
// ---------------------------------------------------------------------------
__global__ __launch_bounds__(WAVE) void pack_mask_kernel(
    const int* __restrict__ mask, unsigned long long* __restrict__ packed,
    int T) {
  const int b = blockIdx.x;
  const int l = threadIdx.x;
  const int* mb = mask + (size_t)b * T;
  const int W = T / 64;
  for (int w = 0; w < W; ++w) {
    unsigned long long bal = __ballot(mb[w * 64 + l] != 0);
    if (l == 0) packed[(size_t)b * W + w] = bal;
  }
}

// ---------------------------------------------------------------------------
// Chunked forward scan (R12-proven structure). Changes this round:
//  - BURN 64 -> 16 (contraction ~0.23/step -> 0.23^16 ~ 6e-11 direction error;
//    cuts per-seq steps 2560 -> 2176).
//  - Inner dot via v_dot2_f32_bf16 when available (17 readlane + 17 dot2 vs
//    33 readlane + 33 fma), f32 accumulation, bf16 = f32 range (no overflow).
//    Guarded by __has_builtin -> falls back to the proven f32 dot.
// ---------------------------------------------------------------------------
__global__ __launch_bounds__(WAVE)
__attribute__((amdgpu_waves_per_eu(4, 4)))
void crf_chunk_kernel(
    const float* __restrict__ emissions,
    const unsigned long long* __restrict__ pmask,
    const float* __restrict__ transitions, const float* __restrict__ start_t,
    const float* __restrict__ end_t, const float* __restrict__ tmask,
    const float* __restrict__ smask, const float* __restrict__ emask,
    float* __restrict__ contrib, int T, int B, int S, int K) {
  const int bid = blockIdx.x;
  const int c = bid / B;
  const int b = bid - c * B;
  const int j = threadIdx.x;
  const int jj = (j < CC) ? j : 0;
  const int W = T / 64;

  __shared__ float s_trans[CC * CC];
  for (int k = j; k < CC * CC; k += WAVE) s_trans[k] = transitions[k] + tmask[k];
  __syncthreads();

#if HAS_BF16DOT
  // lane j holds bf16 pairs (et[2q][j], et[2q+1][j]); zero for lanes >= CC.
  bfv2 etp[17];
#pragma unroll
  for (int q = 0; q < 17; ++q) {
    float v0 = (j < CC) ? __expf(s_trans[(2 * q) * CC + jj]) : 0.f;
    float v1 = (j < CC && 2 * q + 1 < CC)
                   ? __expf(s_trans[(2 * q + 1) * CC + jj]) : 0.f;
    bfv2 e;
    e[0] = (__bf16)v0;
    e[1] = (__bf16)v1;
    etp[q] = e;
  }
#else
  float etv[CC];
#pragma unroll
  for (int i = 0; i < CC; ++i)
    etv[i] = (j < CC) ? __expf(s_trans[i * CC + jj]) : 0.f;
#endif

  const float* __restrict__ emb = emissions + (size_t)b * T * CC;
  const unsigned long long* __restrict__ pkb = pmask + (size_t)b * W;

  const int t_end = ((c + 1) * S < T - 1) ? (c + 1) * S : (T - 1);
  const int t_begin = (c == 0) ? 1 : c * S - (BURN - 1);
  const int NM = (c == 0) ? S / 8 : (S + BURN) / 8;

  float p, logoff = 0.f, Lstart = 0.f;
  if (c == 0) {
    p = (j < CC) ? __expf(start_t[jj] + smask[jj] + emb[jj]) : 0.f;
  } else {
    p = (j < CC) ? 1.0f : 0.f;
  }

  int wcur = t_begin >> 6;
  unsigned long long mw0 = pkb[wcur];
  int wn1 = (wcur + 1 < W) ? wcur + 1 : W - 1;
  unsigned long long mw1 = pkb[wn1];

  float em_pre[8];
#pragma unroll
  for (int k = 0; k < 8; ++k) {
    int tp = t_begin + k;
    tp = tp > T - 1 ? T - 1 : tp;
    em_pre[k] = emb[(size_t)tp * CC + jj];
  }

  int t0 = t_begin;
  for (int mm = 0; mm < NM; ++mm) {
    int w = t0 >> 6;
    if (w != wcur) {
      mw0 = mw1;
      wcur = w;
      int wn = (w + 1 < W) ? w + 1 : W - 1;
      mw1 = pkb[wn];
    }
    int mbit[8];
#pragma unroll
    for (int k = 0; k < 8; ++k) {
      int t = t0 + k;
      unsigned long long mw = ((t >> 6) == wcur) ? mw0 : mw1;
      mbit[k] = (int)((mw >> (t & 63)) & 1ull) & (t <= t_end ? 1 : 0);
    }
#pragma unroll
    for (int k = 0; k < 8; ++k) {
      float emk = em_pre[k];
      int mt = mbit[k];
      {
        int tp = t0 + 8 + k;
        tp = tp < 0 ? 0 : (tp > T - 1 ? T - 1 : tp);
        em_pre[k] = emb[(size_t)tp * CC + jj];
      }
      float eemk = __expf(emk);
#if HAS_BF16DOT
      float pn1 = __shfl(p, j + 1, 64);  // lane 32 reads p_33 = 0 from lane 33
      unsigned ppk;
      asm("v_cvt_pk_bf16_f32 %0, %1, %2" : "=v"(ppk) : "v"(p), "v"(pn1));
      float s = bdot33_bf16(ppk, etp);
#else
      float s = bdot33(p, etv);
#endif
      if ((k & 3) == 0) {
        float r = rl(p, 0);
        float rs = __builtin_amdgcn_rcpf(r);
        float pn = s * (eemk * rs);
        p = mt ? pn : p;
        logoff += mt ? __logf(r) : 0.f;
      } else {
        float pn = s * eemk;
        p = mt ? pn : p;
      }
    }
    t0 += 8;
    if (c > 0 && mm == (BURN / 8 - 1)) {
      Lstart = logoff + __logf(wave_sum64(p));
    }
  }

  float Lend;
  if (c == K - 1) {
    float eendv = (j < CC) ? __expf(end_t[jj] + emask[jj]) : 0.f;
    Lend = logoff + __logf(wave_sum64(p * eendv));
  } else {
    Lend = logoff + __logf(wave_sum64(p));
  }
  if (j == 0) contrib[(size_t)c * B + b] = Lend - Lstart;
}

// ---------------------------------------------------------------------------
// Gold-path score: embarrassingly parallel over (b, t).  (R7-proven)
// ---------------------------------------------------------------------------
__global__ __launch_bounds__(256) void crf_score_kernel(
    const float* __restrict__ emissions, const int* __restrict__ tags,
    const int* __restrict__ mask, const float* __restrict__ transitions,
    const float* __restrict__ start_t, const float* __restrict__ end_t,
    const float* __restrict__ tmask, const float* __restrict__ smask,
    const float* __restrict__ emask, float* __restrict__ score_out, int T) {
  const int b = blockIdx.x;
  const int tid = threadIdx.x;

  __shared__ float s_trans[CC * CC];
  for (int k = tid; k < CC * CC; k += 256) s_trans[k] = transitions[k] + tmask[k];
  __syncthreads();

  const float* __restrict__ emb = emissions + (size_t)b * T * CC;
  const int* __restrict__ tagb = tags + (size_t)b * T;
  const int* __restrict__ maskb = mask + (size_t)b * T;

  float local = 0.f;
  int llen = 0;
  for (int t = tid; t < T; t += 256) {
    int mt = maskb[t];
    llen += (mt != 0);
    if (t >= 1) {
      int cur = tagb[t];
      int prev = tagb[t - 1];
      float v = s_trans[prev * CC + cur] + emb[(size_t)t * CC + cur];
      local += (mt != 0) ? v : 0.f;
    }
  }

  local = wave_sum64(local);
  llen = wave_isum64(llen);
  __shared__ float ws[4];
  __shared__ int wl[4];
  if ((tid & 63) == 0) { ws[tid >> 6] = local; wl[tid >> 6] = llen; }
  __syncthreads();
  if (tid == 0) {
    float total = ws[0] + ws[1] + ws[2] + ws[3];
    int len = wl[0] + wl[1] + wl[2] + wl[3];
    int tag0 = tagb[0];
    total += start_t[tag0] + smask[tag0] + emb[tag0];
    if (len < 1) len = 1;
    int last = tagb[len - 1];
    total += end_t[last] + emask[last];
    score_out[b] = total;
  }
}

// out = mean_b( sum_c contrib[c][b] - score[b] )
__global__ __launch_bounds__(512) void crf_finish_kernel(
    const float* __restrict__ contrib, const float* __restrict__ score,
    float* __restrict__ out, int B, int K) {
  const int b = threadIdx.x;
  float v = 0.f;
  if (b < B) {
    for (int c = 0; c < K; ++c) v += contrib[(size_t)c * B + b];
    v -= score[b];
  }
  v = wave_sum64(v);
  __shared__ float ws[8];
  if ((b & 63) == 0) ws[b >> 6] = v;
  __syncthreads();
  if (b == 0) {
    float s = 0.f;
    for (int q = 0; q < 8; ++q) s += ws[q];
    out[0] = s / (float)B;
  }
}

extern "C" void kernel_launch(void* const* d_in, const int* in_sizes, int n_in,
                              void* d_out, int out_size, void* d_ws, size_t ws_size,
                              hipStream_t stream) {
  const float* emissions = (const float*)d_in[0];
  const int* tags = (const int*)d_in[1];
  const int* mask = (const int*)d_in[2];
  const float* transitions = (const float*)d_in[3];
  const float* start_t = (const float*)d_in[4];
  const float* end_t = (const float*)d_in[5];
  const float* tmask = (const float*)d_in[6];
  const float* smask = (const float*)d_in[7];
  const float* emask = (const float*)d_in[8];

  const int T = 2048;          // fixed problem shape
  const int K = 8;             // chunks per sequence
  const int S = T / K;         // 256
  const int BT = in_sizes[1];  // B*T
  const int B = BT / T;
  const int W = T / 64;

  char* ws = (char*)d_ws;
  unsigned long long* packed = (unsigned long long*)ws;   // B*W u64
  float* contrib = (float*)(ws + (size_t)B * W * 8);      // K*B f
  float* score = contrib + (size_t)K * B;                 // B f

  pack_mask_kernel<<<B, WAVE, 0, stream>>>(mask, packed, T);
  crf_chunk_kernel<<<K * B, WAVE, 0, stream>>>(
      emissions, packed, transitions, start_t, end_t, tmask, smask, emask,
      contrib, T, B, S, K);
  crf_score_kernel<<<B, 256, 0, stream>>>(emissions, tags, mask, transitions,
                                          start_t, end_t, tmask, smask, emask,
                                          score, T);
  crf_finish_kernel<<<1, 512, 0, stream>>>(contrib, score, (float*)d_out, B, K);
}

// Round 14
// 156.241 us; speedup vs baseline: 3.0808x; 1.0477x over previous
//
#include <hip/hip_runtime.h>

#define CC 33
#define WAVE 64
#define BURN 8   // contraction ~0.23/step -> 0.23^8 ~ 8e-6 direction error

#if __has_builtin(__builtin_amdgcn_fdot2_f32_bf16)
#define HAS_BF16DOT 1
typedef __bf16 bfv2 __attribute__((ext_vector_type(2)));
#else
#define HAS_BF16DOT 0
#endif

__device__ __forceinline__ float wave_sum64(float v) {
#pragma unroll
  for (int k = 32; k >= 1; k >>= 1) v += __shfl_xor(v, k, 64);
  return v;
}

__device__ __forceinline__ int wave_isum64(int v) {
#pragma unroll
  for (int k = 32; k >= 1; k >>= 1) v += __shfl_xor(v, k, 64);
  return v;
}

__device__ __forceinline__ float rl(float v, int lane) {
  return __uint_as_float(__builtin_amdgcn_readlane(__float_as_uint(v), lane));
}

// f32 fallback dot: s = sum_i rl(u,i) * etv[i]; 8 accumulators.
__device__ __forceinline__ float bdot33(float u, const float* etv) {
  float a0 = 0.f, a1 = 0.f, a2 = 0.f, a3 = 0.f;
  float a4 = 0.f, a5 = 0.f, a6 = 0.f, a7 = 0.f;
#pragma unroll
  for (int i = 0; i < 32; i += 8) {
    a0 = fmaf(rl(u, i + 0), etv[i + 0], a0);
    a1 = fmaf(rl(u, i + 1), etv[i + 1], a1);
    a2 = fmaf(rl(u, i + 2), etv[i + 2], a2);
    a3 = fmaf(rl(u, i + 3), etv[i + 3], a3);
    a4 = fmaf(rl(u, i + 4), etv[i + 4], a4);
    a5 = fmaf(rl(u, i + 5), etv[i + 5], a5);
    a6 = fmaf(rl(u, i + 6), etv[i + 6], a6);
    a7 = fmaf(rl(u, i + 7), etv[i + 7], a7);
  }
  a0 = fmaf(rl(u, 32), etv[32], a0);
  return (((a0 + a1) + (a2 + a3)) + ((a4 + a5) + (a6 + a7)));
}

#if HAS_BF16DOT
__device__ __forceinline__ bfv2 rlpk(unsigned v, int lane) {
  return __builtin_bit_cast(
      bfv2, (unsigned)__builtin_amdgcn_readlane((int)v, lane));
}
// bf16 dot2 dot: ppk lane i = (bf16(p_i), bf16(p_{i+1})); etp[q] = lane-local
// (etv[2q], etv[2q+1]) pairs. 17 readlane + 17 v_dot2_f32_bf16, f32 accum.
__device__ __forceinline__ float bdot33_bf16(unsigned ppk, const bfv2* etp) {
  float a0 = 0.f, a1 = 0.f, a2 = 0.f, a3 = 0.f;
#pragma unroll
  for (int q = 0; q < 16; q += 4) {
    a0 = __builtin_amdgcn_fdot2_f32_bf16(rlpk(ppk, 2 * q + 0), etp[q + 0], a0, false);
    a1 = __builtin_amdgcn_fdot2_f32_bf16(rlpk(ppk, 2 * q + 2), etp[q + 1], a1, false);
    a2 = __builtin_amdgcn_fdot2_f32_bf16(rlpk(ppk, 2 * q + 4), etp[q + 2], a2, false);
    a3 = __builtin_amdgcn_fdot2_f32_bf16(rlpk(ppk, 2 * q + 6), etp[q + 3], a3, false);
  }
  a0 = __builtin_amdgcn_fdot2_f32_bf16(rlpk(ppk, 32), etp[16], a0, false);
  return (a0 + a1) + (a2 + a3);
}
#endif

// ---------------------------------------------------------------------------
// Pack mask[b][t] (int) into bit-words.
// ---------------------------------------------------------------------------
__global__ __launch_bounds__(WAVE) void pack_mask_kernel(
    const int* __restrict__ mask, unsigned long long* __restrict__ packed,
    int T) {
  const int b = blockIdx.x;
  const int l = threadIdx.x;
  const int* mb = mask + (size_t)b * T;
  const int W = T / 64;
  for (int w = 0; w < W; ++w) {
    unsigned long long bal = __ballot(mb[w * 64 + l] != 0);
    if (l == 0) packed[(size_t)b * W + w] = bal;
  }
}

// ---------------------------------------------------------------------------
// Chunked forward scan (R13-proven inner loop). This round: K=16/S=128/BURN=8
// (work/seq ~unchanged: 2168 vs 2176 steps) with waves_per_eu(8,8) -> 8192
// waves = 8 waves/SIMD (hw max), filling the 26% idle issue slots R13 showed
// (VALUBusy 74% at 4 waves/SIMD; serial p-chain latency unhidden).
// 64-VGPR tier; R13 used 52 so etp/ring should still fit without scratch.
// ---------------------------------------------------------------------------
__global__ __launch_bounds__(WAVE)
__attribute__((amdgpu_waves_per_eu(8, 8)))
void crf_chunk_kernel(
    const float* __restrict__ emissions,
    const unsigned long long* __restrict__ pmask,
    const float* __restrict__ transitions, const float* __restrict__ start_t,
    const float* __restrict__ end_t, const float* __restrict__ tmask,
    const float* __restrict__ smask, const float* __restrict__ emask,
    float* __restrict__ contrib, int T, int B, int S, int K) {
  const int bid = blockIdx.x;
  const int c = bid / B;
  const int b = bid - c * B;
  const int j = threadIdx.x;
  const int jj = (j < CC) ? j : 0;
  const int W = T / 64;

  __shared__ float s_trans[CC * CC];
  for (int k = j; k < CC * CC; k += WAVE) s_trans[k] = transitions[k] + tmask[k];
  __syncthreads();

#if HAS_BF16DOT
  // lane j holds bf16 pairs (et[2q][j], et[2q+1][j]); zero for lanes >= CC.
  bfv2 etp[17];
#pragma unroll
  for (int q = 0; q < 17; ++q) {
    float v0 = (j < CC) ? __expf(s_trans[(2 * q) * CC + jj]) : 0.f;
    float v1 = (j < CC && 2 * q + 1 < CC)
                   ? __expf(s_trans[(2 * q + 1) * CC + jj]) : 0.f;
    bfv2 e;
    e[0] = (__bf16)v0;
    e[1] = (__bf16)v1;
    etp[q] = e;
  }
#else
  float etv[CC];
#pragma unroll
  for (int i = 0; i < CC; ++i)
    etv[i] = (j < CC) ? __expf(s_trans[i * CC + jj]) : 0.f;
#endif

  const float* __restrict__ emb = emissions + (size_t)b * T * CC;
  const unsigned long long* __restrict__ pkb = pmask + (size_t)b * W;

  const int t_end = ((c + 1) * S < T - 1) ? (c + 1) * S : (T - 1);
  const int t_begin = (c == 0) ? 1 : c * S - (BURN - 1);
  const int NM = (c == 0) ? S / 8 : (S + BURN) / 8;

  float p, logoff = 0.f, Lstart = 0.f;
  if (c == 0) {
    p = (j < CC) ? __expf(start_t[jj] + smask[jj] + emb[jj]) : 0.f;
  } else {
    p = (j < CC) ? 1.0f : 0.f;
  }

  int wcur = t_begin >> 6;
  unsigned long long mw0 = pkb[wcur];
  int wn1 = (wcur + 1 < W) ? wcur + 1 : W - 1;
  unsigned long long mw1 = pkb[wn1];

  float em_pre[8];
#pragma unroll
  for (int k = 0; k < 8; ++k) {
    int tp = t_begin + k;
    tp = tp > T - 1 ? T - 1 : tp;
    em_pre[k] = emb[(size_t)tp * CC + jj];
  }

  int t0 = t_begin;
  for (int mm = 0; mm < NM; ++mm) {
    int w = t0 >> 6;
    if (w != wcur) {
      mw0 = mw1;
      wcur = w;
      int wn = (w + 1 < W) ? w + 1 : W - 1;
      mw1 = pkb[wn];
    }
    int mbit[8];
#pragma unroll
    for (int k = 0; k < 8; ++k) {
      int t = t0 + k;
      unsigned long long mw = ((t >> 6) == wcur) ? mw0 : mw1;
      mbit[k] = (int)((mw >> (t & 63)) & 1ull) & (t <= t_end ? 1 : 0);
    }
#pragma unroll
    for (int k = 0; k < 8; ++k) {
      float emk = em_pre[k];
      int mt = mbit[k];
      {
        int tp = t0 + 8 + k;
        tp = tp < 0 ? 0 : (tp > T - 1 ? T - 1 : tp);
        em_pre[k] = emb[(size_t)tp * CC + jj];
      }
      float eemk = __expf(emk);
#if HAS_BF16DOT
      float pn1 = __shfl(p, j + 1, 64);  // lane 32 reads p_33 = 0 from lane 33
      unsigned ppk;
      asm("v_cvt_pk_bf16_f32 %0, %1, %2" : "=v"(ppk) : "v"(p), "v"(pn1));
      float s = bdot33_bf16(ppk, etp);
#else
      float s = bdot33(p, etv);
#endif
      if ((k & 3) == 0) {
        float r = rl(p, 0);
        float rs = __builtin_amdgcn_rcpf(r);
        float pn = s * (eemk * rs);
        p = mt ? pn : p;
        logoff += mt ? __logf(r) : 0.f;
      } else {
        float pn = s * eemk;
        p = mt ? pn : p;
      }
    }
    t0 += 8;
    if (c > 0 && mm == (BURN / 8 - 1)) {
      Lstart = logoff + __logf(wave_sum64(p));
    }
  }

  float Lend;
  if (c == K - 1) {
    float eendv = (j < CC) ? __expf(end_t[jj] + emask[jj]) : 0.f;
    Lend = logoff + __logf(wave_sum64(p * eendv));
  } else {
    Lend = logoff + __logf(wave_sum64(p));
  }
  if (j == 0) contrib[(size_t)c * B + b] = Lend - Lstart;
}

// ---------------------------------------------------------------------------
// Gold-path score: embarrassingly parallel over (b, t).  (R7-proven)
// ---------------------------------------------------------------------------
__global__ __launch_bounds__(256) void crf_score_kernel(
    const float* __restrict__ emissions, const int* __restrict__ tags,
    const int* __restrict__ mask, const float* __restrict__ transitions,
    const float* __restrict__ start_t, const float* __restrict__ end_t,
    const float* __restrict__ tmask, const float* __restrict__ smask,
    const float* __restrict__ emask, float* __restrict__ score_out, int T) {
  const int b = blockIdx.x;
  const int tid = threadIdx.x;

  __shared__ float s_trans[CC * CC];
  for (int k = tid; k < CC * CC; k += 256) s_trans[k] = transitions[k] + tmask[k];
  __syncthreads();

  const float* __restrict__ emb = emissions + (size_t)b * T * CC;
  const int* __restrict__ tagb = tags + (size_t)b * T;
  const int* __restrict__ maskb = mask + (size_t)b * T;

  float local = 0.f;
  int llen = 0;
  for (int t = tid; t < T; t += 256) {
    int mt = maskb[t];
    llen += (mt != 0);
    if (t >= 1) {
      int cur = tagb[t];
      int prev = tagb[t - 1];
      float v = s_trans[prev * CC + cur] + emb[(size_t)t * CC + cur];
      local += (mt != 0) ? v : 0.f;
    }
  }

  local = wave_sum64(local);
  llen = wave_isum64(llen);
  __shared__ float ws[4];
  __shared__ int wl[4];
  if ((tid & 63) == 0) { ws[tid >> 6] = local; wl[tid >> 6] = llen; }
  __syncthreads();
  if (tid == 0) {
    float total = ws[0] + ws[1] + ws[2] + ws[3];
    int len = wl[0] + wl[1] + wl[2] + wl[3];
    int tag0 = tagb[0];
    total += start_t[tag0] + smask[tag0] + emb[tag0];
    if (len < 1) len = 1;
    int last = tagb[len - 1];
    total += end_t[last] + emask[last];
    score_out[b] = total;
  }
}

// out = mean_b( sum_c contrib[c][b] - score[b] )
__global__ __launch_bounds__(512) void crf_finish_kernel(
    const float* __restrict__ contrib, const float* __restrict__ score,
    float* __restrict__ out, int B, int K) {
  const int b = threadIdx.x;
  float v = 0.f;
  if (b < B) {
    for (int c = 0; c < K; ++c) v += contrib[(size_t)c * B + b];
    v -= score[b];
  }
  v = wave_sum64(v);
  __shared__ float ws[8];
  if ((b & 63) == 0) ws[b >> 6] = v;
  __syncthreads();
  if (b == 0) {
    float s = 0.f;
    for (int q = 0; q < 8; ++q) s += ws[q];
    out[0] = s / (float)B;
  }
}

extern "C" void kernel_launch(void* const* d_in, const int* in_sizes, int n_in,
                              void* d_out, int out_size, void* d_ws, size_t ws_size,
                              hipStream_t stream) {
  const float* emissions = (const float*)d_in[0];
  const int* tags = (const int*)d_in[1];
  const int* mask = (const int*)d_in[2];
  const float* transitions = (const float*)d_in[3];
  const float* start_t = (const float*)d_in[4];
  const float* end_t = (const float*)d_in[5];
  const float* tmask = (const float*)d_in[6];
  const float* smask = (const float*)d_in[7];
  const float* emask = (const float*)d_in[8];

  const int T = 2048;          // fixed problem shape
  const int K = 16;            // chunks per sequence
  const int S = T / K;         // 128
  const int BT = in_sizes[1];  // B*T
  const int B = BT / T;
  const int W = T / 64;

  char* ws = (char*)d_ws;
  unsigned long long* packed = (unsigned long long*)ws;   // B*W u64
  float* contrib = (float*)(ws + (size_t)B * W * 8);      // K*B f
  float* score = contrib + (size_t)K * B;                 // B f

  pack_mask_kernel<<<B, WAVE, 0, stream>>>(mask, packed, T);
  crf_chunk_kernel<<<K * B, WAVE, 0, stream>>>(
      emissions, packed, transitions, start_t, end_t, tmask, smask, emask,
      contrib, T, B, S, K);
  crf_score_kernel<<<B, 256, 0, stream>>>(emissions, tags, mask, transitions,
                                          start_t, end_t, tmask, smask, emask,
                                          score, T);
  crf_finish_kernel<<<1, 512, 0, stream>>>(contrib, score, (float*)d_out, B, K);
}

// Round 15
// 148.975 us; speedup vs baseline: 3.2310x; 1.0488x over previous
//
#include <hip/hip_runtime.h>

#define CC 33
#define WAVE 64
#define BURN 8   // contraction ~0.23/step -> 0.23^8 ~ 8e-6 direction error

#if __has_builtin(__builtin_amdgcn_fdot2_f32_bf16)
#define HAS_BF16DOT 1
typedef __bf16 bfv2 __attribute__((ext_vector_type(2)));
#else
#define HAS_BF16DOT 0
#endif

__device__ __forceinline__ float wave_sum64(float v) {
#pragma unroll
  for (int k = 32; k >= 1; k >>= 1) v += __shfl_xor(v, k, 64);
  return v;
}

__device__ __forceinline__ float rl(float v, int lane) {
  return __uint_as_float(__builtin_amdgcn_readlane(__float_as_uint(v), lane));
}

// f32 fallback dot: s = sum_i rl(u,i) * etv[i]; 8 accumulators.
__device__ __forceinline__ float bdot33(float u, const float* etv) {
  float a0 = 0.f, a1 = 0.f, a2 = 0.f, a3 = 0.f;
  float a4 = 0.f, a5 = 0.f, a6 = 0.f, a7 = 0.f;
#pragma unroll
  for (int i = 0; i < 32; i += 8) {
    a0 = fmaf(rl(u, i + 0), etv[i + 0], a0);
    a1 = fmaf(rl(u, i + 1), etv[i + 1], a1);
    a2 = fmaf(rl(u, i + 2), etv[i + 2], a2);
    a3 = fmaf(rl(u, i + 3), etv[i + 3], a3);
    a4 = fmaf(rl(u, i + 4), etv[i + 4], a4);
    a5 = fmaf(rl(u, i + 5), etv[i + 5], a5);
    a6 = fmaf(rl(u, i + 6), etv[i + 6], a6);
    a7 = fmaf(rl(u, i + 7), etv[i + 7], a7);
  }
  a0 = fmaf(rl(u, 32), etv[32], a0);
  return (((a0 + a1) + (a2 + a3)) + ((a4 + a5) + (a6 + a7)));
}

#if HAS_BF16DOT
__device__ __forceinline__ bfv2 rlpk(unsigned v, int lane) {
  return __builtin_bit_cast(
      bfv2, (unsigned)__builtin_amdgcn_readlane((int)v, lane));
}
// bf16 dot2 dot: ppk lane i = (bf16(p_i), bf16(p_{i+1})); etp[q] = lane-local
// (etv[2q], etv[2q+1]) pairs. 17 readlane + 17 v_dot2_f32_bf16, f32 accum.
__device__ __forceinline__ float bdot33_bf16(unsigned ppk, const bfv2* etp) {
  float a0 = 0.f, a1 = 0.f, a2 = 0.f, a3 = 0.f;
#pragma unroll
  for (int q = 0; q < 16; q += 4) {
    a0 = __builtin_amdgcn_fdot2_f32_bf16(rlpk(ppk, 2 * q + 0), etp[q + 0], a0, false);
    a1 = __builtin_amdgcn_fdot2_f32_bf16(rlpk(ppk, 2 * q + 2), etp[q + 1], a1, false);
    a2 = __builtin_amdgcn_fdot2_f32_bf16(rlpk(ppk, 2 * q + 4), etp[q + 2], a2, false);
    a3 = __builtin_amdgcn_fdot2_f32_bf16(rlpk(ppk, 2 * q + 6), etp[q + 3], a3, false);
  }
  a0 = __builtin_amdgcn_fdot2_f32_bf16(rlpk(ppk, 32), etp[16], a0, false);
  return (a0 + a1) + (a2 + a3);
}
#endif

// ---------------------------------------------------------------------------
// Pack mask[b][t] (int) into bit-words + sequence lengths (popcount).
// ---------------------------------------------------------------------------
__global__ __launch_bounds__(WAVE) void pack_mask_kernel(
    const int* __restrict__ mask, unsigned long long* __restrict__ packed,
    int* __restrict__ lengths, int T) {
  const int b = blockIdx.x;
  const int l = threadIdx.x;
  const int* mb = mask + (size_t)b * T;
  const int W = T / 64;
  int cnt = 0;
  for (int w = 0; w < W; ++w) {
    unsigned long long bal = __ballot(mb[w * 64 + l] != 0);
    if (l == 0) {
      packed[(size_t)b * W + w] = bal;
      cnt += __popcll(bal);
    }
  }
  if (l == 0) lengths[b] = cnt;
}

// ---------------------------------------------------------------------------
// Chunked forward scan (R14-proven inner loop, untouched) + FUSED gold-path
// score: each chunk-block also computes the score contribution of its owned
// span t in [c*S+1, t_end] (2 gathers/lane over the whole kernel) and folds
// -score_span into contrib[c][b]. Chunk 0 adds the start term. The end term
// (tags[len-1]-dependent) is applied in the finish kernel. This removes the
// separate crf_score_kernel (~16 us serial on the same stream).
// ---------------------------------------------------------------------------
__global__ __launch_bounds__(WAVE)
__attribute__((amdgpu_waves_per_eu(8, 8)))
void crf_chunk_kernel(
    const float* __restrict__ emissions,
    const unsigned long long* __restrict__ pmask,
    const int* __restrict__ tags, const int* __restrict__ mask,
    const float* __restrict__ transitions, const float* __restrict__ start_t,
    const float* __restrict__ end_t, const float* __restrict__ tmask,
    const float* __restrict__ smask, const float* __restrict__ emask,
    float* __restrict__ contrib, int T, int B, int S, int K) {
  const int bid = blockIdx.x;
  const int c = bid / B;
  const int b = bid - c * B;
  const int j = threadIdx.x;
  const int jj = (j < CC) ? j : 0;
  const int W = T / 64;

  __shared__ float s_trans[CC * CC];
  for (int k = j; k < CC * CC; k += WAVE) s_trans[k] = transitions[k] + tmask[k];
  __syncthreads();

#if HAS_BF16DOT
  // lane j holds bf16 pairs (et[2q][j], et[2q+1][j]); zero for lanes >= CC.
  bfv2 etp[17];
#pragma unroll
  for (int q = 0; q < 17; ++q) {
    float v0 = (j < CC) ? __expf(s_trans[(2 * q) * CC + jj]) : 0.f;
    float v1 = (j < CC && 2 * q + 1 < CC)
                   ? __expf(s_trans[(2 * q + 1) * CC + jj]) : 0.f;
    bfv2 e;
    e[0] = (__bf16)v0;
    e[1] = (__bf16)v1;
    etp[q] = e;
  }
#else
  float etv[CC];
#pragma unroll
  for (int i = 0; i < CC; ++i)
    etv[i] = (j < CC) ? __expf(s_trans[i * CC + jj]) : 0.f;
#endif

  const float* __restrict__ emb = emissions + (size_t)b * T * CC;
  const unsigned long long* __restrict__ pkb = pmask + (size_t)b * W;
  const int* __restrict__ tagb = tags + (size_t)b * T;
  const int* __restrict__ maskb = mask + (size_t)b * T;

  const int t_end = ((c + 1) * S < T - 1) ? (c + 1) * S : (T - 1);
  const int t_begin = (c == 0) ? 1 : c * S - (BURN - 1);
  const int NM = (c == 0) ? S / 8 : (S + BURN) / 8;

  float p, logoff = 0.f, Lstart = 0.f;
  if (c == 0) {
    p = (j < CC) ? __expf(start_t[jj] + smask[jj] + emb[jj]) : 0.f;
  } else {
    p = (j < CC) ? 1.0f : 0.f;
  }

  // ---- fused score for owned span [c*S+1, t_end]: 2 gathers per lane ----
  float sc = 0.f;
  {
    const int t1 = c * S + 1 + j;
#pragma unroll
    for (int r = 0; r < 2; ++r) {
      int t = t1 + r * WAVE;
      if (t <= t_end) {
        int mt = maskb[t];
        int cur = tagb[t];
        int prev = tagb[t - 1];
        float v = s_trans[prev * CC + cur] + emb[(size_t)t * CC + cur];
        sc += (mt != 0) ? v : 0.f;
      }
    }
    if (c == 0 && j == 0) {
      int tag0 = tagb[0];
      sc += start_t[tag0] + smask[tag0] + emb[tag0];
    }
    sc = wave_sum64(sc);
  }

  int wcur = t_begin >> 6;
  unsigned long long mw0 = pkb[wcur];
  int wn1 = (wcur + 1 < W) ? wcur + 1 : W - 1;
  unsigned long long mw1 = pkb[wn1];

  float em_pre[8];
#pragma unroll
  for (int k = 0; k < 8; ++k) {
    int tp = t_begin + k;
    tp = tp > T - 1 ? T - 1 : tp;
    em_pre[k] = emb[(size_t)tp * CC + jj];
  }

  int t0 = t_begin;
  for (int mm = 0; mm < NM; ++mm) {
    int w = t0 >> 6;
    if (w != wcur) {
      mw0 = mw1;
      wcur = w;
      int wn = (w + 1 < W) ? w + 1 : W - 1;
      mw1 = pkb[wn];
    }
    int mbit[8];
#pragma unroll
    for (int k = 0; k < 8; ++k) {
      int t = t0 + k;
      unsigned long long mw = ((t >> 6) == wcur) ? mw0 : mw1;
      mbit[k] = (int)((mw >> (t & 63)) & 1ull) & (t <= t_end ? 1 : 0);
    }
#pragma unroll
    for (int k = 0; k < 8; ++k) {
      float emk = em_pre[k];
      int mt = mbit[k];
      {
        int tp = t0 + 8 + k;
        tp = tp < 0 ? 0 : (tp > T - 1 ? T - 1 : tp);
        em_pre[k] = emb[(size_t)tp * CC + jj];
      }
      float eemk = __expf(emk);
#if HAS_BF16DOT
      float pn1 = __shfl(p, j + 1, 64);  // lane 32 reads p_33 = 0 from lane 33
      unsigned ppk;
      asm("v_cvt_pk_bf16_f32 %0, %1, %2" : "=v"(ppk) : "v"(p), "v"(pn1));
      float s = bdot33_bf16(ppk, etp);
#else
      float s = bdot33(p, etv);
#endif
      if ((k & 3) == 0) {
        float r = rl(p, 0);
        float rs = __builtin_amdgcn_rcpf(r);
        float pn = s * (eemk * rs);
        p = mt ? pn : p;
        logoff += mt ? __logf(r) : 0.f;
      } else {
        float pn = s * eemk;
        p = mt ? pn : p;
      }
    }
    t0 += 8;
    if (c > 0 && mm == (BURN / 8 - 1)) {
      Lstart = logoff + __logf(wave_sum64(p));
    }
  }

  float Lend;
  if (c == K - 1) {
    float eendv = (j < CC) ? __expf(end_t[jj] + emask[jj]) : 0.f;
    Lend = logoff + __logf(wave_sum64(p * eendv));
  } else {
    Lend = logoff + __logf(wave_sum64(p));
  }
  if (j == 0) contrib[(size_t)c * B + b] = (Lend - Lstart) - sc;
}

// out = mean_b( sum_c contrib[c][b] - end_term[b] );  end_term via lengths.
__global__ __launch_bounds__(512) void crf_finish_kernel(
    const float* __restrict__ contrib, const int* __restrict__ tags,
    const int* __restrict__ lengths, const float* __restrict__ end_t,
    const float* __restrict__ emask, float* __restrict__ out, int B, int K,
    int T) {
  const int b = threadIdx.x;  // one thread per sequence (B == 512)
  float v = 0.f;
  if (b < B) {
    for (int c = 0; c < K; ++c) v += contrib[(size_t)c * B + b];
    int len = lengths[b];
    if (len < 1) len = 1;
    int last = tags[(size_t)b * T + len - 1];
    v -= end_t[last] + emask[last];
  }
  v = wave_sum64(v);
  __shared__ float ws[8];
  if ((b & 63) == 0) ws[b >> 6] = v;
  __syncthreads();
  if (b == 0) {
    float s = 0.f;
    for (int q = 0; q < 8; ++q) s += ws[q];
    out[0] = s / (float)B;
  }
}

extern "C" void kernel_launch(void* const* d_in, const int* in_sizes, int n_in,
                              void* d_out, int out_size, void* d_ws, size_t ws_size,
                              hipStream_t stream) {
  const float* emissions = (const float*)d_in[0];
  const int* tags = (const int*)d_in[1];
  const int* mask = (const int*)d_in[2];
  const float* transitions = (const float*)d_in[3];
  const float* start_t = (const float*)d_in[4];
  const float* end_t = (const float*)d_in[5];
  const float* tmask = (const float*)d_in[6];
  const float* smask = (const float*)d_in[7];
  const float* emask = (const float*)d_in[8];

  const int T = 2048;          // fixed problem shape
  const int K = 16;            // chunks per sequence
  const int S = T / K;         // 128
  const int BT = in_sizes[1];  // B*T
  const int B = BT / T;
  const int W = T / 64;

  char* ws = (char*)d_ws;
  unsigned long long* packed = (unsigned long long*)ws;   // B*W u64
  float* contrib = (float*)(ws + (size_t)B * W * 8);      // K*B f
  int* lengths = (int*)(contrib + (size_t)K * B);         // B i32

  pack_mask_kernel<<<B, WAVE, 0, stream>>>(mask, packed, lengths, T);
  crf_chunk_kernel<<<K * B, WAVE, 0, stream>>>(
      emissions, packed, tags, mask, transitions, start_t, end_t, tmask, smask,
      emask, contrib, T, B, S, K);
  crf_finish_kernel<<<1, 512, 0, stream>>>(contrib, tags, lengths, end_t,
                                           emask, (float*)d_out, B, K, T);
}